// Round 1
// baseline (1439.925 us; speedup 1.0000x reference)
//
#include <hip/hip_runtime.h>
#include <math.h>

#define COLS 4096
#define COLS4 1024  // COLS / 4

// ---------------------------------------------------------------------------
// Stage 1: per-chunk column min/max partials — FILL-PATTERN (moving window).
// Thread global-id g owns float4 index g + k*G (G = total threads). G is a
// multiple of COLS4, so each thread stays pinned to one float4-column:
//   f4col = g & 1023,  rows visited = (g >> 10) + Q*k
// where Q = nblocks/4 is the number of partial chunks. This reproduces the
// rocclr fill kernel's linear instantaneous footprint exactly (consecutive
// lanes/blocks -> consecutive 16 B), spreading every wavefront of accesses
// across all HBM channels, instead of 1024 lockstep streams 1 MB apart.
// Unroll x8 => 8 loads in flight per wave; grid 4096 blocks => 8 blocks/CU
// (32 waves/CU, max occupancy) for the x stream.
// Partial layout [Q][COLS] is identical to the previous version, so the
// reduce tree is unchanged: block b writes chunk q = b>>2, f4col slice
// ((b&3)*256 + t).
// ---------------------------------------------------------------------------
__global__ __launch_bounds__(256) void col_minmax_stage1_lin(
    const float* __restrict__ src, int Q, int iters,
    float* __restrict__ ws_min, float* __restrict__ ws_max)
{
    const int b = blockIdx.x;
    const int t = threadIdx.x;
    const int f4col = ((b & 3) << 8) | t;   // [0, 1024)
    const int q     = b >> 2;               // chunk index [0, Q)

    const size_t stride = (size_t)Q * COLS4;  // in float4 units (= G threads)
    const float4* p = (const float4*)src + (size_t)q * COLS4 + f4col;

    float4 mn = make_float4( INFINITY,  INFINITY,  INFINITY,  INFINITY);
    float4 mx = make_float4(-INFINITY, -INFINITY, -INFINITY, -INFINITY);

    for (int k = 0; k < iters; k += 8) {
        float4 v[8];
#pragma unroll
        for (int u = 0; u < 8; ++u)
            v[u] = p[(size_t)u * stride];
        p += 8 * stride;
#pragma unroll
        for (int u = 0; u < 8; ++u) {
            mn.x = fminf(mn.x, v[u].x); mx.x = fmaxf(mx.x, v[u].x);
            mn.y = fminf(mn.y, v[u].y); mx.y = fmaxf(mx.y, v[u].y);
            mn.z = fminf(mn.z, v[u].z); mx.z = fmaxf(mx.z, v[u].z);
            mn.w = fminf(mn.w, v[u].w); mx.w = fmaxf(mx.w, v[u].w);
        }
    }

    ((float4*)ws_min)[(size_t)q * COLS4 + f4col] = mn;
    ((float4*)ws_max)[(size_t)q * COLS4 + f4col] = mx;
}

// ---------------------------------------------------------------------------
// Merged chunk-partial reducer: handles TWO independent reductions (x and w)
// in one launch, selected by blockIdx.y. grid.x*256 threads cover COLS4
// float4-columns; consecutive threads read consecutive float4 -> coalesced.
// ---------------------------------------------------------------------------
__global__ __launch_bounds__(256) void col_minmax_reduce2(
    const float* __restrict__ a_in_min, const float* __restrict__ a_in_max,
    int a_n, int a_cpg, int a_groups,
    float* __restrict__ a_out_min, float* __restrict__ a_out_max,
    const float* __restrict__ b_in_min, const float* __restrict__ b_in_max,
    int b_n, int b_cpg,
    float* __restrict__ b_out_min, float* __restrict__ b_out_max)
{
    int c4 = blockIdx.x * 256 + threadIdx.x;
    if (c4 >= COLS4) return;

    const float* im; const float* ix; float* om; float* ox;
    int g, k0, k1;
    if ((int)blockIdx.y < a_groups) {
        g = blockIdx.y;
        im = a_in_min; ix = a_in_max; om = a_out_min; ox = a_out_max;
        k0 = g * a_cpg; k1 = k0 + a_cpg; if (k1 > a_n) k1 = a_n;
    } else {
        g = blockIdx.y - a_groups;
        im = b_in_min; ix = b_in_max; om = b_out_min; ox = b_out_max;
        k0 = g * b_cpg; k1 = k0 + b_cpg; if (k1 > b_n) k1 = b_n;
    }

    float4 mn = make_float4( INFINITY,  INFINITY,  INFINITY,  INFINITY);
    float4 mx = make_float4(-INFINITY, -INFINITY, -INFINITY, -INFINITY);
    for (int k = k0; k < k1; ++k) {
        float4 a = ((const float4*)im)[(size_t)k * COLS4 + c4];
        float4 b = ((const float4*)ix)[(size_t)k * COLS4 + c4];
        mn.x = fminf(mn.x, a.x); mx.x = fmaxf(mx.x, b.x);
        mn.y = fminf(mn.y, a.y); mx.y = fmaxf(mx.y, b.y);
        mn.z = fminf(mn.z, a.z); mx.z = fmaxf(mx.z, b.z);
        mn.w = fminf(mn.w, a.w); mx.w = fmaxf(mx.w, b.w);
    }
    ((float4*)om)[(size_t)g * COLS4 + c4] = mn;
    ((float4*)ox)[(size_t)g * COLS4 + c4] = mx;
}

// ---------------------------------------------------------------------------
// Row min/max + FIRST-OCCURRENCE argmin/argmax. One 256-thread block per row.
// Runs after w's column stage1, so w (64 MB) is Infinity-Cache-resident and
// this second pass is ~free in HBM terms. Per-thread strict compare over
// ascending indices keeps first occurrence; cross-thread lexicographic
// (value, index) LDS tree reduction. Indices stored as float32 (exact).
// ---------------------------------------------------------------------------
__global__ __launch_bounds__(256) void row_minmax_arg(
    const float* __restrict__ w,
    float* __restrict__ out_min, float* __restrict__ out_max,
    float* __restrict__ out_imin, float* __restrict__ out_imax)
{
    __shared__ float s_mn[256], s_mx[256];
    __shared__ int   s_in[256], s_ix[256];

    int row = blockIdx.x;
    const float4* w4 = (const float4*)(w + (size_t)row * COLS);

    float mn = INFINITY, mx = -INFINITY;
    int imn = 0, imx = 0;
#pragma unroll
    for (int u = 0; u < COLS4 / 256; ++u) {
        int i = u * 256 + threadIdx.x;
        float4 v = w4[i];
        int b = i << 2;
        if (v.x < mn) { mn = v.x; imn = b;     }
        if (v.x > mx) { mx = v.x; imx = b;     }
        if (v.y < mn) { mn = v.y; imn = b + 1; }
        if (v.y > mx) { mx = v.y; imx = b + 1; }
        if (v.z < mn) { mn = v.z; imn = b + 2; }
        if (v.z > mx) { mx = v.z; imx = b + 2; }
        if (v.w < mn) { mn = v.w; imn = b + 3; }
        if (v.w > mx) { mx = v.w; imx = b + 3; }
    }

    int t = threadIdx.x;
    s_mn[t] = mn; s_in[t] = imn;
    s_mx[t] = mx; s_ix[t] = imx;
    __syncthreads();

    for (int s = 128; s > 0; s >>= 1) {
        if (t < s) {
            float ov = s_mn[t + s]; int oi = s_in[t + s];
            if (ov < s_mn[t] || (ov == s_mn[t] && oi < s_in[t])) { s_mn[t] = ov; s_in[t] = oi; }
            ov = s_mx[t + s]; oi = s_ix[t + s];
            if (ov > s_mx[t] || (ov == s_mx[t] && oi < s_ix[t])) { s_mx[t] = ov; s_ix[t] = oi; }
        }
        __syncthreads();
    }

    if (t == 0) {
        out_min[row]  = s_mn[0];
        out_max[row]  = s_mx[0];
        out_imin[row] = (float)s_in[0];
        out_imax[row] = (float)s_ix[0];
    }
}

extern "C" void kernel_launch(void* const* d_in, const int* in_sizes, int n_in,
                              void* d_out, int out_size, void* d_ws, size_t ws_size,
                              hipStream_t stream) {
    const float* x = (const float*)d_in[0];
    const float* w = (const float*)d_in[1];
    float* out = (float*)d_out;

    int rows_x = in_sizes[0] / COLS;  // 65536
    int rows_w = in_sizes[1] / COLS;  // 4096

    // x: 4096 blocks -> Q=1024 chunks, 64 iterations each (rows/Q).
    const int chunks_x = 1024, g2_x = 32;
    // w: 1024 blocks -> Q=256 chunks, 16 iterations each.
    const int chunks_w = 256, g2_w = 8;
    int iters_x = rows_x / chunks_x;  // 64
    int iters_w = rows_w / chunks_w;  // 16

    // Workspace layout (ws is >= 4 GB; we use < 50 MB).
    float* ws_min_x  = (float*)d_ws;
    float* ws_max_x  = ws_min_x  + (size_t)chunks_x * COLS;
    float* ws2_min_x = ws_max_x  + (size_t)chunks_x * COLS;
    float* ws2_max_x = ws2_min_x + (size_t)g2_x * COLS;
    float* ws_min_w  = ws2_max_x + (size_t)g2_x * COLS;
    float* ws_max_w  = ws_min_w  + (size_t)chunks_w * COLS;
    float* ws2_min_w = ws_max_w  + (size_t)chunks_w * COLS;
    float* ws2_max_w = ws2_min_w + (size_t)g2_w * COLS;

    float* x_min     = out + 0 * COLS;
    float* x_max     = out + 1 * COLS;
    float* w_col_min = out + 2 * COLS;
    float* w_col_max = out + 3 * COLS;
    float* w_row_min = out + 4 * COLS;
    float* w_row_max = out + 5 * COLS;
    float* w_imin    = out + 6 * COLS;
    float* w_imax    = out + 7 * COLS;

    dim3 blk(256);

    // x column stats: fill-pattern linear walk (the 1.07 GB stream).
    col_minmax_stage1_lin<<<dim3(chunks_x * 4), blk, 0, stream>>>(
        x, chunks_x, iters_x, ws_min_x, ws_max_x);
    // w column stats (loads w into LLC for the row pass).
    col_minmax_stage1_lin<<<dim3(chunks_w * 4), blk, 0, stream>>>(
        w, chunks_w, iters_w, ws_min_w, ws_max_w);
    // w row stats + argmin/argmax (w is LLC-resident now).
    row_minmax_arg<<<dim3(rows_w), blk, 0, stream>>>(
        w, w_row_min, w_row_max, w_imin, w_imax);

    // Level 1: x 1024 -> 32 groups, w 256 -> 8 groups, one launch.
    col_minmax_reduce2<<<dim3(COLS4 / 256, g2_x + g2_w), blk, 0, stream>>>(
        ws_min_x, ws_max_x, chunks_x, chunks_x / g2_x, g2_x, ws2_min_x, ws2_max_x,
        ws_min_w, ws_max_w, chunks_w, chunks_w / g2_w, ws2_min_w, ws2_max_w);
    // Level 2: x 32 -> 1, w 8 -> 1, one launch.
    col_minmax_reduce2<<<dim3(COLS4 / 256, 2), blk, 0, stream>>>(
        ws2_min_x, ws2_max_x, g2_x, g2_x, 1, x_min, x_max,
        ws2_min_w, ws2_max_w, g2_w, g2_w, w_col_min, w_col_max);
}